// Round 1
// baseline (223.807 us; speedup 1.0000x reference)
//
#include <hip/hip_runtime.h>
#include <math.h>

// Fused Canny+dilate: one kernel, all intermediates in LDS.
// Tile = 32x32 outputs; halos: gray +-6, blur +-4, mag/idx +-3, masked +-2.
#define TILE 32
#define GSZ  44   // TILE + 12 (gray)
#define BSZ  40   // TILE + 8  (blurred)
#define MSZ  38   // TILE + 6  (mag / octant idx)
#define KSZ  36   // TILE + 4  (nms-masked mag)

__global__ __launch_bounds__(256)
void canny_fused(const float* __restrict__ x, float* __restrict__ out) {
    __shared__ float         s_gray[GSZ][GSZ];
    __shared__ float         s_blur[BSZ][BSZ];
    __shared__ float         s_mag [MSZ][MSZ];
    __shared__ unsigned char s_idx [MSZ][MSZ];
    __shared__ float         s_msk [KSZ][KSZ];

    const int tid = threadIdx.x;
    const int n   = blockIdx.z;
    const int ty0 = blockIdx.y * TILE;
    const int tx0 = blockIdx.x * TILE;

    const float* x0 = x + (size_t)n * 3 * 512 * 512;

    // ---- stage 1: gray (channel-reversed weights: 0.299*c2 + 0.587*c1 + 0.114*c0)
    for (int i = tid; i < GSZ * GSZ; i += 256) {
        int ly = i / GSZ, lx = i % GSZ;
        int gy = ty0 - 6 + ly, gx = tx0 - 6 + lx;
        float v = 0.f;
        if (gy >= 0 && gy < 512 && gx >= 0 && gx < 512) {
            size_t o = (size_t)gy * 512 + gx;
            v = 0.299f * x0[2 * 512 * 512 + o]
              + 0.587f * x0[1 * 512 * 512 + o]
              + 0.114f * x0[o];
        }
        s_gray[ly][lx] = v;
    }
    __syncthreads();

    // Gaussian ksize=5 sigma=1 weights (f32-rounded)
    const float GKW[5] = {0.054488684549643f, 0.244201342003233f,
                          0.402619946931554f, 0.244201342003233f,
                          0.054488684549643f};

    // ---- stage 2: 5x5 Gaussian blur, reflect padding (index -1 -> 1, 512 -> 510)
    for (int i = tid; i < BSZ * BSZ; i += 256) {
        int ly = i / BSZ, lx = i % BSZ;
        int gy = ty0 - 4 + ly, gx = tx0 - 4 + lx;
        float v = 0.f;
        if (gy >= 0 && gy < 512 && gx >= 0 && gx < 512) {
            float acc = 0.f;
            #pragma unroll
            for (int a = 0; a < 5; ++a) {
                int yy = gy + a - 2;
                yy = yy < 0 ? -yy : (yy > 511 ? 1022 - yy : yy);
                const float* row = s_gray[yy - (ty0 - 6)];
                float racc = 0.f;
                #pragma unroll
                for (int b = 0; b < 5; ++b) {
                    int xx = gx + b - 2;
                    xx = xx < 0 ? -xx : (xx > 511 ? 1022 - xx : xx);
                    racc += GKW[b] * row[xx - (tx0 - 6)];
                }
                acc += GKW[a] * racc;
            }
            v = acc;
        }
        s_blur[ly][lx] = v;
    }
    __syncthreads();

    // ---- stage 3: Sobel (edge clamp) -> mag, octant index
    for (int i = tid; i < MSZ * MSZ; i += 256) {
        int ly = i / MSZ, lx = i % MSZ;
        int gy = ty0 - 3 + ly, gx = tx0 - 3 + lx;
        float magv = 0.f;
        unsigned char idx = 0;
        if (gy >= 0 && gy < 512 && gx >= 0 && gx < 512) {
            int ym = max(gy - 1, 0)   - (ty0 - 4);
            int y0 = gy               - (ty0 - 4);
            int yp = min(gy + 1, 511) - (ty0 - 4);
            int xm = max(gx - 1, 0)   - (tx0 - 4);
            int xc = gx               - (tx0 - 4);
            int xp = min(gx + 1, 511) - (tx0 - 4);
            float b00 = s_blur[ym][xm], b01 = s_blur[ym][xc], b02 = s_blur[ym][xp];
            float b10 = s_blur[y0][xm],                       b12 = s_blur[y0][xp];
            float b20 = s_blur[yp][xm], b21 = s_blur[yp][xc], b22 = s_blur[yp][xp];
            float gxv = 0.125f * (b02 - b00) + 0.25f * (b12 - b10) + 0.125f * (b22 - b20);
            float gyv = 0.125f * (b20 - b00) + 0.25f * (b21 - b01) + 0.125f * (b22 - b02);
            magv = sqrtf(gxv * gxv + gyv * gyv + 1e-6f);
            float ang = rintf(atan2f(gyv, gxv) * 57.29577951308232f / 45.0f);
            int ai = (int)ang;              // in [-4, 4]
            idx = (unsigned char)(((ai % 8) + 8) % 8);
        }
        s_mag[ly][lx] = magv;
        s_idx[ly][lx] = idx;
    }
    __syncthreads();

    // ---- stage 4: NMS mask (mag neighbors zero-padded outside image)
    const int offy[8] = {0, 1, 1, 1, 0, -1, -1, -1};
    const int offx[8] = {1, 1, 0, -1, -1, -1, 0, 1};
    for (int i = tid; i < KSZ * KSZ; i += 256) {
        int ly = i / KSZ, lx = i % KSZ;
        int gy = ty0 - 2 + ly, gx = tx0 - 2 + lx;
        float v = 0.f;
        if (gy >= 0 && gy < 512 && gx >= 0 && gx < 512) {
            int my = gy - (ty0 - 3), mx = gx - (tx0 - 3);
            float m = s_mag[my][mx];
            int d = s_idx[my][mx];
            int dy = offy[d], dx = offx[d];
            float mp = 0.f, mn = 0.f;
            if (gy + dy >= 0 && gy + dy < 512 && gx + dx >= 0 && gx + dx < 512)
                mp = s_mag[my + dy][mx + dx];
            if (gy - dy >= 0 && gy - dy < 512 && gx - dx >= 0 && gx - dx < 512)
                mn = s_mag[my - dy][mx - dx];
            float pos = m - mp, neg = m - mn;
            v = (fminf(pos, neg) > 0.f) ? m : 0.f;
        }
        s_msk[ly][lx] = v;
    }
    __syncthreads();

    // ---- stage 5: 5x5 max-dilate. masked >= 0 and the window always contains
    // the in-image center, so the -10000 pad of the reference never wins; the
    // 0-filled out-of-image LDS entries are equally harmless.
    for (int i = tid; i < TILE * TILE; i += 256) {
        int ly = i / TILE, lx = i % TILE;
        int gy = ty0 + ly, gx = tx0 + lx;
        float best = 0.f;
        #pragma unroll
        for (int a = 0; a < 5; ++a)
            #pragma unroll
            for (int b = 0; b < 5; ++b)
                best = fmaxf(best, s_msk[ly + a][lx + b]);
        out[((size_t)n * 512 + gy) * 512 + gx] = best;
    }
}

extern "C" void kernel_launch(void* const* d_in, const int* in_sizes, int n_in,
                              void* d_out, int out_size, void* d_ws, size_t ws_size,
                              hipStream_t stream) {
    const float* x = (const float*)d_in[0];
    float* out = (float*)d_out;
    dim3 grid(512 / TILE, 512 / TILE, 32);
    canny_fused<<<grid, 256, 0, stream>>>(x, out);
}

// Round 2
// 213.616 us; speedup vs baseline: 1.0477x; 1.0477x over previous
//
#include <hip/hip_runtime.h>
#include <math.h>

// Fused Canny+dilate, round 2: separable blur, reflect-at-load, atan2-free
// octant axis classifier, separable dilate, LDS region reuse.
// Tile = 32x32 outputs; halos: gray +-6, blur +-4, mag/idx +-3, masked +-2.
#define TILE 32
#define GSZ  44   // gray rows/cols    [t0-6, t0+37]
#define BSZ  40   // blurred           [t0-4, t0+35]
#define MSZ  38   // mag / axis        [t0-3, t0+34]
#define KSZ  36   // nms-masked mag    [t0-2, t0+33]

// LDS layout (bytes). msk/col overlay regions that are dead by the time
// they are written (gray dead after h-blur; h-blur dead after v-blur).
#define OFF_GRAY 0                         // 44*44*4 = 7744, dead after 2a
#define OFF_HB   7744                      // 44*40*4 = 7040, dead after 2b
#define OFF_BLUR 14784                     // 40*40*4 = 6400
#define OFF_MAG  21184                     // 38*38*4 = 5776
#define OFF_IDX  26960                     // 38*38   = 1444
#define OFF_MSK  0                         // 36*36*4 = 5184 (overlay gray)
#define OFF_COL  7744                      // 36*32*4 = 4608 (overlay hb)
#define SMEM_BYTES 28416

__device__ __forceinline__ int reflect512(int i) {
    // valid for i in [-511, 1022]; matches reflect-pad of width 2 on [0,512)
    int a = i < 0 ? -i : i;
    int b = 1022 - a;
    return a < b ? a : b;
}

__global__ __launch_bounds__(256)
void canny_fused(const float* __restrict__ x, float* __restrict__ out) {
    __shared__ __align__(16) unsigned char smem[SMEM_BYTES];
    float (*s_gray)[GSZ]       = (float(*)[GSZ])(smem + OFF_GRAY);
    float (*s_hb)[BSZ]         = (float(*)[BSZ])(smem + OFF_HB);
    float (*s_blur)[BSZ]       = (float(*)[BSZ])(smem + OFF_BLUR);
    float (*s_mag)[MSZ]        = (float(*)[MSZ])(smem + OFF_MAG);
    unsigned char (*s_idx)[MSZ]= (unsigned char(*)[MSZ])(smem + OFF_IDX);
    float (*s_msk)[KSZ]        = (float(*)[KSZ])(smem + OFF_MSK);
    float (*s_col)[TILE]       = (float(*)[TILE])(smem + OFF_COL);

    const int tid = threadIdx.x;
    const int n   = blockIdx.z;
    const int ty0 = blockIdx.y * TILE;
    const int tx0 = blockIdx.x * TILE;

    const float* x0 = x + (size_t)n * 3 * 512 * 512;

    // ---- stage 1: gray with reflect applied at load time.
    // Channel-reversed weights: 0.299*c2 + 0.587*c1 + 0.114*c0.
    // Out-of-range halo (beyond the +-2 the reference reflects) yields
    // harmless values never consumed by a valid blurred pixel.
    for (int i = tid; i < GSZ * GSZ; i += 256) {
        int ly = i / GSZ, lx = i - ly * GSZ;
        int gy = reflect512(ty0 - 6 + ly);
        int gx = reflect512(tx0 - 6 + lx);
        size_t o = (size_t)gy * 512 + gx;
        s_gray[ly][lx] = 0.299f * x0[2 * 512 * 512 + o]
                       + 0.587f * x0[1 * 512 * 512 + o]
                       + 0.114f * x0[o];
    }
    __syncthreads();

    const float GKW0 = 0.054488684549643f;
    const float GKW1 = 0.244201342003233f;
    const float GKW2 = 0.402619946931554f;

    // ---- stage 2a: horizontal blur (44 rows x 40 cols), no index math
    for (int i = tid; i < GSZ * BSZ; i += 256) {
        int ly = i / BSZ, lx = i - ly * BSZ;
        const float* r = &s_gray[ly][lx];
        s_hb[ly][lx] = GKW0 * r[0] + GKW1 * r[1] + GKW2 * r[2]
                     + GKW1 * r[3] + GKW0 * r[4];
    }
    __syncthreads();

    // ---- stage 2b: vertical blur (40 x 40)
    for (int i = tid; i < BSZ * BSZ; i += 256) {
        int ly = i / BSZ, lx = i - ly * BSZ;
        s_blur[ly][lx] = GKW0 * s_hb[ly][lx]     + GKW1 * s_hb[ly + 1][lx]
                       + GKW2 * s_hb[ly + 2][lx] + GKW1 * s_hb[ly + 3][lx]
                       + GKW0 * s_hb[ly + 4][lx];
    }
    __syncthreads();

    // ---- stage 3: Sobel (edge clamp) -> mag, gradient axis (octant mod 4)
    for (int i = tid; i < MSZ * MSZ; i += 256) {
        int ly = i / MSZ, lx = i - ly * MSZ;
        int gy = ty0 - 3 + ly, gx = tx0 - 3 + lx;
        float magv = 0.f;
        unsigned char axis = 0;
        if (gy >= 0 && gy < 512 && gx >= 0 && gx < 512) {
            int ym = max(gy - 1, 0)   - (ty0 - 4);
            int y0 = gy               - (ty0 - 4);
            int yp = min(gy + 1, 511) - (ty0 - 4);
            int xm = max(gx - 1, 0)   - (tx0 - 4);
            int xc = gx               - (tx0 - 4);
            int xp = min(gx + 1, 511) - (tx0 - 4);
            float b00 = s_blur[ym][xm], b01 = s_blur[ym][xc], b02 = s_blur[ym][xp];
            float b10 = s_blur[y0][xm],                       b12 = s_blur[y0][xp];
            float b20 = s_blur[yp][xm], b21 = s_blur[yp][xc], b22 = s_blur[yp][xp];
            float gxv = 0.125f * (b02 - b00) + 0.25f * (b12 - b10) + 0.125f * (b22 - b20);
            float gyv = 0.125f * (b20 - b00) + 0.25f * (b21 - b01) + 0.125f * (b22 - b02);
            magv = sqrtf(gxv * gxv + gyv * gyv + 1e-6f);
            // octant = round(atan2/45deg) mod 8; NMS uses +-offset so only
            // octant mod 4 matters. Boundaries at tan(22.5), tan(67.5).
            float ax = fabsf(gxv), ay = fabsf(gyv);
            if (ay <= 0.41421356237309515f * ax)      axis = 0;  // (0,1)
            else if (ay >= 2.4142135623730951f * ax)  axis = 2;  // (1,0)
            else axis = ((gxv >= 0.f) == (gyv >= 0.f)) ? 1 : 3;  // (1,1)/(1,-1)
        }
        s_mag[ly][lx] = magv;
        s_idx[ly][lx] = axis;
    }
    __syncthreads();

    // ---- stage 4: NMS mask (neighbors zero-padded outside image)
    const int offy[4] = {0, 1, 1, 1};
    const int offx[4] = {1, 1, 0, -1};
    for (int i = tid; i < KSZ * KSZ; i += 256) {
        int ly = i / KSZ, lx = i - ly * KSZ;
        int gy = ty0 - 2 + ly, gx = tx0 - 2 + lx;
        float v = 0.f;
        if (gy >= 0 && gy < 512 && gx >= 0 && gx < 512) {
            int my = ly + 1, mx = lx + 1;   // mag base is (t0-3)
            float m = s_mag[my][mx];
            int d = s_idx[my][mx];
            int dy = offy[d], dx = offx[d];
            float mp = 0.f, mn = 0.f;
            if (gy + dy >= 0 && gy + dy < 512 && gx + dx >= 0 && gx + dx < 512)
                mp = s_mag[my + dy][mx + dx];
            if (gy - dy >= 0 && gy - dy < 512 && gx - dx >= 0 && gx - dx < 512)
                mn = s_mag[my - dy][mx - dx];
            v = (fminf(m - mp, m - mn) > 0.f) ? m : 0.f;
        }
        s_msk[ly][lx] = v;
    }
    __syncthreads();

    // ---- stage 5a: horizontal 5-max (36 rows x 32 cols)
    for (int i = tid; i < KSZ * TILE; i += 256) {
        int ly = i / TILE, lx = i - ly * TILE;
        const float* r = &s_msk[ly][lx];
        float m01 = fmaxf(r[0], r[1]);
        float m23 = fmaxf(r[2], r[3]);
        s_col[ly][lx] = fmaxf(fmaxf(m01, m23), r[4]);
    }
    __syncthreads();

    // ---- stage 5b: vertical 5-max -> output. Masked mag >= 0 and every
    // window contains an in-image center, so the reference's -1e4 pad and
    // our zero-filled out-of-image entries never win.
    for (int i = tid; i < TILE * TILE; i += 256) {
        int ly = i / TILE, lx = i - ly * TILE;
        float m01 = fmaxf(s_col[ly][lx],     s_col[ly + 1][lx]);
        float m23 = fmaxf(s_col[ly + 2][lx], s_col[ly + 3][lx]);
        float best = fmaxf(fmaxf(m01, m23), s_col[ly + 4][lx]);
        out[((size_t)n * 512 + ty0 + ly) * 512 + tx0 + lx] = best;
    }
}

extern "C" void kernel_launch(void* const* d_in, const int* in_sizes, int n_in,
                              void* d_out, int out_size, void* d_ws, size_t ws_size,
                              hipStream_t stream) {
    const float* x = (const float*)d_in[0];
    float* out = (float*)d_out;
    dim3 grid(512 / TILE, 512 / TILE, 32);
    canny_fused<<<grid, 256, 0, stream>>>(x, out);
}

// Round 3
// 175.083 us; speedup vs baseline: 1.2783x; 1.2201x over previous
//
#include <hip/hip_runtime.h>
#include <math.h>

// Round 3: wave-per-strip register pipeline. No LDS, no barriers.
// Each 64-lane wave owns a 64-wide x strip (52 out cols, 6-lane halo/side)
// and streams down y with register ring buffers; x-neighbors via ds_bpermute.
#define IMW 512
#define SEG 32
#define NSEG (512/SEG)     // 16
#define NSTRIP 10          // 10*52 = 520 >= 512
#define OUTW 52

__device__ __forceinline__ int reflect512(int i) {   // valid for i in [-511,1022]
    int a = i < 0 ? -i : i;
    int b = 1022 - a;
    return a < b ? a : b;
}
__device__ __forceinline__ float bperm(int a4, float v) {
    return __int_as_float(__builtin_amdgcn_ds_bpermute(a4, __float_as_int(v)));
}

__global__ __launch_bounds__(256)
void canny_pipe(const float* __restrict__ x, float* __restrict__ out) {
    const int lane  = threadIdx.x & 63;
    const int unit  = blockIdx.x * 4 + (threadIdx.x >> 6);
    const int img   = unit / (NSTRIP * NSEG);
    const int rem   = unit - img * (NSTRIP * NSEG);
    const int strip = rem / NSEG;
    const int seg   = rem - strip * NSEG;
    const int Y0 = seg * SEG, Y1 = Y0 + SEG;
    const int x0 = strip * OUTW - 6;
    const int xv = x0 + lane;                  // virtual x (may be OOB)
    const int xr = reflect512(xv);             // load column (reflect pad in x)
    const bool inimg  = (xv >= 0) && (xv < IMW);
    const bool stlane = (lane >= 6) && (lane < 58) && (xv < IMW);
    const int l4  = lane << 2;
    // sobel h-pass clamped-neighbor lanes (edge clamp in x)
    const int aL4 = (min(max(xv - 1, 0), 511) - x0) << 2;
    const int aR4 = (min(max(xv + 1, 0), 511) - x0) << 2;

    const float* base = x + (size_t)img * 3 * IMW * IMW;
    const float* c0p = base + (size_t)0 * IMW * IMW + xr;
    const float* c1p = base + (size_t)1 * IMW * IMW + xr;
    const float* c2p = base + (size_t)2 * IMW * IMW + xr;
    float* outp = out + (size_t)img * IMW * IMW + xv;

    const float K0 = 0.054488684549643f, K1 = 0.244201342003233f, K2 = 0.402619946931554f;

    // ring buffers (shift registers); index grows with row
    float hb0=0,hb1=0,hb2=0,hb3=0,hb4=0;          // h-blurred gray, rows v-4..v
    float hx0=0,hx1=0,hx2=0, hy0=0,hy1=0,hy2=0;   // sobel h-passes, rows v-4..v-2
    float mg0=0,mg1=0,mg2=0;                      // magnitude, rows v-5..v-3
    int   ax0=0, ax1=0;                           // axis, rows v-4, v-3
    float cm0=0,cm1=0,cm2=0,cm3=0,cm4=0;          // col-max of msk, rows v-8..v-4

    // prefetch gray row for v = Y0-6
    int r0 = reflect512(Y0 - 6);
    float p0 = c0p[(size_t)r0 * IMW];
    float p1 = c1p[(size_t)r0 * IMW];
    float p2 = c2p[(size_t)r0 * IMW];

    for (int v = Y0 - 6; v <= Y1 + 5; ++v) {
        // ---- gray row v (channel-reversed weights) + prefetch row v+1
        float gray = 0.299f * p2 + 0.587f * p1 + 0.114f * p0;
        int rn = reflect512(v + 1);
        p0 = c0p[(size_t)rn * IMW];
        p1 = c1p[(size_t)rn * IMW];
        p2 = c2p[(size_t)rn * IMW];

        // ---- h-blur (x reflect already baked into per-lane loads)
        float gl1 = bperm(l4 - 4, gray), gl2 = bperm(l4 - 8, gray);
        float gr1 = bperm(l4 + 4, gray), gr2 = bperm(l4 + 8, gray);
        hb0 = hb1; hb1 = hb2; hb2 = hb3; hb3 = hb4;
        hb4 = K0 * (gl2 + gr2) + K1 * (gl1 + gr1) + K2 * gray;

        // ---- v-blur -> blurred row v-2; sobel h-passes (edge-clamped x)
        float blur = K0 * (hb0 + hb4) + K1 * (hb1 + hb3) + K2 * hb2;
        float bl = bperm(aL4, blur), br = bperm(aR4, blur);
        hx0 = hx1; hx1 = hx2; hx2 = br - bl;
        hy0 = hy1; hy1 = hy2; hy2 = bl + 2.f * blur + br;

        // ---- sobel v-pass + mag + axis, row g = v-3 (edge-clamped y)
        int g = v - 3;
        float hxa = (g == 0)   ? hx1 : hx0;
        float hxc = (g == 511) ? hx1 : hx2;
        float hya = (g == 0)   ? hy1 : hy0;
        float hyc = (g == 511) ? hy1 : hy2;
        float gxv = (hxa + 2.f * hx1 + hxc) * 0.125f;
        float gyv = (hyc - hya) * 0.125f;
        float mag = sqrtf(gxv * gxv + gyv * gyv + 1e-6f);
        float axm = fabsf(gxv), aym = fabsf(gyv);
        int axis;
        if (aym <= 0.41421356237309515f * axm)      axis = 0;  // (0,+-1)
        else if (aym >= 2.4142135623730951f * axm)  axis = 2;  // (+-1,0)
        else axis = ((gxv >= 0.f) == (gyv >= 0.f)) ? 1 : 3;    // diagonals
        mg0 = mg1; mg1 = mg2; mg2 = inimg ? mag : 0.f;
        ax0 = ax1; ax1 = axis;

        // ---- NMS + mask, row m = v-4 (zero-pad y and x via zeroed lanes)
        int m = v - 4;
        float magm = (m == 0)   ? 0.f : mg0;   // row m-1
        float magc = mg1;                      // row m
        float magp = (m == 511) ? 0.f : mg2;   // row m+1
        // gather neighbor values per source row, select by MY axis afterwards
        float gcp = bperm(l4 + 4, magc), gcm = bperm(l4 - 4, magc);
        float gpp = bperm(l4 + 4, magp), gpm = bperm(l4 - 4, magp);
        float gmm = bperm(l4 - 4, magm), gmp = bperm(l4 + 4, magm);
        int d = ax0;
        float mp = (d == 0) ? gcp : (d == 1) ? gpp : (d == 2) ? magp : gpm;
        float mn = (d == 0) ? gcm : (d == 1) ? gmm : (d == 2) ? magm : gmp;
        float msk = (inimg && fminf(magc - mp, magc - mn) > 0.f) ? magc : 0.f;

        // ---- horizontal 5-max -> colmax row m
        float s1 = fmaxf(bperm(l4 - 4, msk), bperm(l4 + 4, msk));
        float s2 = fmaxf(bperm(l4 - 8, msk), bperm(l4 + 8, msk));
        cm0 = cm1; cm1 = cm2; cm2 = cm3; cm3 = cm4;
        cm4 = fmaxf(fmaxf(s1, s2), msk);

        // ---- vertical 5-max -> out row y = v-6 (zero-pad y; msk >= 0)
        int y = v - 6;
        if (y >= Y0) {
            float c0 = (y >= 2)   ? cm0 : 0.f;
            float c1 = (y >= 1)   ? cm1 : 0.f;
            float c3 = (y <= 510) ? cm3 : 0.f;
            float c4 = (y <= 509) ? cm4 : 0.f;
            float val = fmaxf(fmaxf(fmaxf(c0, c1), fmaxf(cm2, c3)), c4);
            if (stlane) outp[(size_t)y * IMW] = val;
        }
    }
}

extern "C" void kernel_launch(void* const* d_in, const int* in_sizes, int n_in,
                              void* d_out, int out_size, void* d_ws, size_t ws_size,
                              hipStream_t stream) {
    const float* x = (const float*)d_in[0];
    float* out = (float*)d_out;
    const int units = 32 * NSTRIP * NSEG;   // 5120 waves
    dim3 grid(units / 4);                   // 4 waves per 256-thread block
    canny_pipe<<<grid, 256, 0, stream>>>(x, out);
}